// Round 2
// baseline (628.886 us; speedup 1.0000x reference)
//
#include <hip/hip_runtime.h>
#include <hip/hip_bf16.h>

#define N_AGENTS 50000
#define N_NEI    1600000
#define ROWS     128
#define PHI_BLOCKS (N_NEI / ROWS)   // 12500, exact

typedef __bf16 bf16_t;
typedef __attribute__((ext_vector_type(8))) __bf16 bf16x8;
typedef __attribute__((ext_vector_type(4))) float  f32x4;

#define SO 66   // fp32 outb leading dim: bank = (8q + m16) % 32 -> exact 2-way (free)

// ws layout (float units)
#define WS_SUMM   0            // 50000*64 = 3,200,000 f  (atomic-accumulated pooled H1)
#define WS_CNT    3200000      // 50000 f                 (per-agent neighbor count)
#define WS_WC     3250000      // 4096 f  Wc = phi_w2 @ rho_w1 (fp32, exact fold)
#define WS_BC     3254096      // 64 f    bc = phi_b2 @ rho_w1
#define WS_W1PK   3254160      // 4096 bf16 = 2048 f, 16B-aligned (13,016,640 % 16 == 0)
#define WS_ZERO_F 3250000      // floats to zero (summ + cnt)

// ---------------------------------------------------------------------------
// prep: block 0 packs W1^T (bf16) into MFMA B-fragment order:
//   frag[tn=n>>4][kb=k>>5][lane=(n&15)+16*((k>>3)&3)][j=k&7]
// so phi can stage it with global_load_lds (wave-uniform base + lane*16) and
// read fragments as lane-contiguous ds_read_b128 (zero bank conflicts).
// block 1 computes the GEMM2 fold: Wc = phi_w2 @ rho_w1, bc = phi_b2 @ rho_w1.
// ---------------------------------------------------------------------------
__global__ __launch_bounds__(256) void prep_kernel(
    const float* __restrict__ w1g, const float* __restrict__ w2g,
    const float* __restrict__ b2g, const float* __restrict__ rw1g,
    unsigned short* __restrict__ w1pack, float* __restrict__ Wc,
    float* __restrict__ bc)
{
  const int tid = threadIdx.x;
  if (blockIdx.x == 0) {
    for (int i = tid; i < 4096; i += 256) {
      int k = i >> 6, n = i & 63;              // w1g is [k][n] row-major
      int tn = n >> 4, kb = k >> 5;
      int l  = (n & 15) + 16 * ((k >> 3) & 3);
      int j  = k & 7;
      bf16_t bv = (bf16_t)w1g[i];
      w1pack[((tn * 2 + kb) * 64 + l) * 8 + j] = *(unsigned short*)&bv;
    }
  } else {
    for (int i = tid; i < 4096; i += 256) {
      int h = i >> 6, n = i & 63;
      float s = 0.f;
      #pragma unroll 8
      for (int o = 0; o < 64; ++o) s = fmaf(w2g[h * 64 + o], rw1g[o * 64 + n], s);
      Wc[i] = s;
    }
    if (tid < 64) {
      float s = 0.f;
      for (int o = 0; o < 64; ++o) s = fmaf(b2g[o], rw1g[o * 64 + tid], s);
      bc[tid] = s;
    }
  }
}

// ---------------------------------------------------------------------------
// phi: per block of 128 sorted rows: H1 = relu(X@W1+b1) via bf16 MFMA
// (fragment-major LDS, conflict-free), then per-wave segmented column-sum of
// H1 over its own 32 rows -> atomicAdd into summH1 + run-length into cnt.
// GEMM2 is folded into rho via Wc (exact fp32) -- not computed here.
// ---------------------------------------------------------------------------
__global__ __launch_bounds__(256, 4) void phi_kernel(
    const float* __restrict__ nb, const float* __restrict__ b1g,
    const int* __restrict__ seg, const unsigned short* __restrict__ w1pack,
    float* __restrict__ summH1, float* __restrict__ cnt)
{
  __shared__ __align__(16) union {
    struct {
      bf16_t Afr[16 * 64 * 8];  // [tile*2+kb][lane][j]  16 KB : X A-fragments
      bf16_t Wfr[8 * 64 * 8];   // [tn*2+kb][lane][j]     8 KB : W1 B-fragments
    } s;
    float outb[ROWS * SO];      // 33792 B : H1 fp32 (aliases frags + 9.2 KB)
  } u;
  __shared__ float biasf[64];
  __shared__ int sid[ROWS];

  const int tid  = threadIdx.x;
  const int w    = tid >> 6;
  const int lane = tid & 63;
  const int m16  = lane & 15;
  const int q    = lane >> 4;
  const long base = (long)blockIdx.x * ROWS;

  if (tid < ROWS) sid[tid] = seg[base + tid];
  if (tid < 64)  biasf[tid] = b1g[tid];

  // ---- W1 fragments: async global->LDS, 1 KB per instruction, no VALU
  #pragma unroll
  for (int c = 0; c < 2; ++c) {
    int chunk = w * 2 + c;  // 8 x 1KB chunks, wave-distributed
    __builtin_amdgcn_global_load_lds(
        (const __attribute__((address_space(1))) void*)(w1pack + chunk * 512 + lane * 8),
        (__attribute__((address_space(3))) void*)(&u.s.Wfr[chunk * 512]),
        16, 0, 0);
  }

  // ---- X tile -> bf16 A-fragments (lane-contiguous b128 writes, 0 conflicts)
  #pragma unroll
  for (int it = 0; it < 4; ++it) {
    int tile = 2 * w + (it >> 1), kb = it & 1;   // wave stages its own 2 tiles
    int row = tile * 16 + m16;
    const float4* g = (const float4*)(nb + (base + row) * 64 + kb * 32 + q * 8);
    float4 v0 = g[0], v1 = g[1];
    bf16x8 p = { (bf16_t)v0.x, (bf16_t)v0.y, (bf16_t)v0.z, (bf16_t)v0.w,
                 (bf16_t)v1.x, (bf16_t)v1.y, (bf16_t)v1.z, (bf16_t)v1.w };
    *(bf16x8*)&u.s.Afr[((tile * 2 + kb) * 64 + lane) * 8] = p;
  }
  __syncthreads();   // drains vmcnt (global_load_lds) + lgkm

  // ---- fragment loads: lane*16 contiguous -> zero bank conflicts
  bf16x8 afr[2][2], bfr[4][2];
  #pragma unroll
  for (int tm = 0; tm < 2; ++tm)
    #pragma unroll
    for (int kb = 0; kb < 2; ++kb)
      afr[tm][kb] = *(const bf16x8*)&u.s.Afr[(((2 * w + tm) * 2 + kb) * 64 + lane) * 8];
  #pragma unroll
  for (int tn = 0; tn < 4; ++tn)
    #pragma unroll
    for (int kb = 0; kb < 2; ++kb)
      bfr[tn][kb] = *(const bf16x8*)&u.s.Wfr[((tn * 2 + kb) * 64 + lane) * 8];

  f32x4 acc[2][4];
  #pragma unroll
  for (int tm = 0; tm < 2; ++tm)
    #pragma unroll
    for (int tn = 0; tn < 4; ++tn) {
      f32x4 a = {0.f, 0.f, 0.f, 0.f};
      a = __builtin_amdgcn_mfma_f32_16x16x32_bf16(afr[tm][0], bfr[tn][0], a, 0, 0, 0);
      a = __builtin_amdgcn_mfma_f32_16x16x32_bf16(afr[tm][1], bfr[tn][1], a, 0, 0, 0);
      acc[tm][tn] = a;
    }
  __syncthreads();   // all frag reads done; outb may overwrite frag memory

  // ---- H1 (bias+relu) -> outb fp32; D layout: row=q*4+i, col=tn*16+m16
  const int rb = w * 32;
  #pragma unroll
  for (int tm = 0; tm < 2; ++tm)
    #pragma unroll
    for (int tn = 0; tn < 4; ++tn) {
      float bv = biasf[tn * 16 + m16];
      #pragma unroll
      for (int i = 0; i < 4; ++i)
        u.outb[(rb + tm * 16 + q * 4 + i) * SO + tn * 16 + m16] =
            fmaxf(acc[tm][tn][i] + bv, 0.f);
    }

  // ---- segmented reduction: wave owns rows [rb,rb+32), lane owns col=lane.
  // sorted ids -> run detection; one wave-atomic per run (+1 lane-0 cnt add).
  float racc = 0.f;
  int runlen = 0;
  for (int r = rb; r < rb + 32; ++r) {
    racc += u.outb[r * SO + lane];
    ++runlen;
    int sr = sid[r];
    if (r == rb + 31 || sid[r + 1] != sr) {
      atomicAdd(summH1 + (long)sr * 64 + lane, racc);
      if (lane == 0) atomicAdd(cnt + sr, (float)runlen);
      racc = 0.f;
      runlen = 0;
    }
  }
}

// ---------------------------------------------------------------------------
// rho: fp32 throughout. h = relu(summH1 @ Wc + cnt*bc + rho_b1),
// out = h @ rho_w2 + rho_b2. One thread per agent, LDS-broadcast weights.
// ---------------------------------------------------------------------------
__global__ __launch_bounds__(256) void rho_kernel(
    const float* __restrict__ summH1, const float* __restrict__ cnt,
    const float* __restrict__ Wc, const float* __restrict__ bc,
    const float* __restrict__ rb1g, const float* __restrict__ rw2g,
    const float* __restrict__ rb2g, float* __restrict__ out)
{
  __shared__ float sW[64 * 64];
  __shared__ float sbc[64], sb1[64], sw2[128], sb2[2];
  const int tid = threadIdx.x;
  for (int i = tid; i < 4096; i += 256) sW[i] = Wc[i];
  if (tid < 64)  { sbc[tid] = bc[tid]; sb1[tid] = rb1g[tid]; }
  if (tid < 128) sw2[tid] = rw2g[tid];
  if (tid < 2)   sb2[tid] = rb2g[tid];
  __syncthreads();

  int a = blockIdx.x * 256 + tid;
  if (a >= N_AGENTS) return;

  float x[64];
  const float4* xr = (const float4*)(summH1 + (long)a * 64);
  #pragma unroll
  for (int i = 0; i < 16; ++i) {
    float4 v = xr[i];
    x[4 * i] = v.x; x[4 * i + 1] = v.y; x[4 * i + 2] = v.z; x[4 * i + 3] = v.w;
  }
  float c = cnt[a];

  float o0 = sb2[0], o1 = sb2[1];
  for (int n = 0; n < 64; ++n) {
    float a0 = fmaf(c, sbc[n], sb1[n]), a1 = 0.f, a2 = 0.f, a3 = 0.f;
    #pragma unroll
    for (int k = 0; k < 64; k += 4) {
      a0 = fmaf(x[k],     sW[(k)     * 64 + n], a0);
      a1 = fmaf(x[k + 1], sW[(k + 1) * 64 + n], a1);
      a2 = fmaf(x[k + 2], sW[(k + 2) * 64 + n], a2);
      a3 = fmaf(x[k + 3], sW[(k + 3) * 64 + n], a3);
    }
    float h = fmaxf((a0 + a1) + (a2 + a3), 0.f);
    o0 = fmaf(h, sw2[2 * n],     o0);
    o1 = fmaf(h, sw2[2 * n + 1], o1);
  }
  *(float2*)(out + (long)a * 2) = make_float2(o0, o1);
}

// ---------------------------------------------------------------------------
extern "C" void kernel_launch(void* const* d_in, const int* in_sizes, int n_in,
                              void* d_out, int out_size, void* d_ws, size_t ws_size,
                              hipStream_t stream) {
  const float* neighbors = (const float*)d_in[0];
  const float* phi_w1    = (const float*)d_in[1];
  const float* phi_b1    = (const float*)d_in[2];
  const float* phi_w2    = (const float*)d_in[3];
  const float* phi_b2    = (const float*)d_in[4];
  const float* rho_w1    = (const float*)d_in[5];
  const float* rho_b1    = (const float*)d_in[6];
  const float* rho_w2    = (const float*)d_in[7];
  const float* rho_b2    = (const float*)d_in[8];
  const int*   seg       = (const int*)d_in[9];
  float* out = (float*)d_out;

  float* ws     = (float*)d_ws;
  float* summH1 = ws + WS_SUMM;
  float* cntp   = ws + WS_CNT;
  float* Wc     = ws + WS_WC;
  float* bc     = ws + WS_BC;
  unsigned short* w1pack = (unsigned short*)(ws + WS_W1PK);

  hipMemsetAsync(ws, 0, (size_t)WS_ZERO_F * sizeof(float), stream);
  prep_kernel<<<2, 256, 0, stream>>>(phi_w1, phi_w2, phi_b2, rho_w1,
                                     w1pack, Wc, bc);
  phi_kernel<<<PHI_BLOCKS, 256, 0, stream>>>(neighbors, phi_b1, seg, w1pack,
                                             summH1, cntp);
  rho_kernel<<<(N_AGENTS + 255) / 256, 256, 0, stream>>>(summH1, cntp, Wc, bc,
                                                         rho_b1, rho_w2, rho_b2, out);
}

// Round 3
// 626.471 us; speedup vs baseline: 1.0039x; 1.0039x over previous
//
#include <hip/hip_runtime.h>
#include <hip/hip_bf16.h>

#define N_AGENTS 50000
#define N_NEI    1600000
#define ROWS     128
#define PHI_BLOCKS (N_NEI / ROWS)   // 12500, exact

typedef __bf16 bf16_t;
typedef __attribute__((ext_vector_type(8))) __bf16 bf16x8;
typedef __attribute__((ext_vector_type(4))) float  f32x4;

#define SO 66   // fp32 outb leading dim: bank = (8q + m16) % 32 -> exact 2-way (free)

// ws layout (float units)
#define WS_SUMM   0            // 50000*64 = 3,200,000 f  (atomic-accumulated pooled H1)
#define WS_CNT    3200000      // 50000 f                 (per-agent neighbor count)
#define WS_W1PK   3250000      // 4096 bf16 = 2048 f, byte off 13,000,000 (16B aligned)
#define WS_ZERO_F 3250000      // floats to zero (summ + cnt)

// ---------------------------------------------------------------------------
// prep: single tiny block packs W1^T (bf16) into MFMA B-fragment order:
//   frag[tn=n>>4][kb=k>>5][lane=(n&15)+16*((k>>3)&3)][j=k&7]
// so phi stages it with global_load_lds (wave-uniform base + lane*16) and
// reads fragments as lane-contiguous ds_read_b128 (zero bank conflicts).
// The GEMM2 fold (Wc = phi_w2 @ rho_w1) moved into rho's prologue: a 2-block
// prep serialized 10-20 us of latency-bound compute ahead of phi (R2 +22us).
// ---------------------------------------------------------------------------
__global__ __launch_bounds__(256) void prep_kernel(
    const float* __restrict__ w1g, unsigned short* __restrict__ w1pack)
{
  const int tid = threadIdx.x;
  for (int i = tid; i < 4096; i += 256) {
    int k = i >> 6, n = i & 63;              // w1g is [k][n] row-major
    int tn = n >> 4, kb = k >> 5;
    int l  = (n & 15) + 16 * ((k >> 3) & 3);
    int j  = k & 7;
    bf16_t bv = (bf16_t)w1g[i];
    w1pack[((tn * 2 + kb) * 64 + l) * 8 + j] = *(unsigned short*)&bv;
  }
}

// ---------------------------------------------------------------------------
// phi: per block of 128 sorted rows: H1 = relu(X@W1+b1) via bf16 MFMA
// (fragment-major LDS, conflict-free), then per-wave segmented column-sum of
// H1 over its own 32 rows -> atomicAdd into summH1 + run-length into cnt.
// GEMM2 is folded into rho via Wc (exact fp32) -- not computed here.
// All global loads are issued before any LDS/scalar work so the staging
// latency overlaps the w1pack DMA (memory-bound kernel: 32 KB/block read).
// ---------------------------------------------------------------------------
__global__ __launch_bounds__(256, 4) void phi_kernel(
    const float* __restrict__ nb, const float* __restrict__ b1g,
    const int* __restrict__ seg, const unsigned short* __restrict__ w1pack,
    float* __restrict__ summH1, float* __restrict__ cnt)
{
  __shared__ __align__(16) union {
    struct {
      bf16_t Afr[16 * 64 * 8];  // [tile*2+kb][lane][j]  16 KB : X A-fragments
      bf16_t Wfr[8 * 64 * 8];   // [tn*2+kb][lane][j]     8 KB : W1 B-fragments
    } s;
    float outb[ROWS * SO];      // 33792 B : H1 fp32 (aliases frags + 9.2 KB)
  } u;
  __shared__ float biasf[64];
  __shared__ int sid[ROWS];

  const int tid  = threadIdx.x;
  const int w    = tid >> 6;
  const int lane = tid & 63;
  const int m16  = lane & 15;
  const int q    = lane >> 4;
  const long base = (long)blockIdx.x * ROWS;

  // ---- issue ALL global loads first (8 dwordx4 X + seg + bias in flight)
  float4 xv[4][2];
  #pragma unroll
  for (int it = 0; it < 4; ++it) {
    int tile = 2 * w + (it >> 1), kb = it & 1;   // wave stages its own 2 tiles
    int row = tile * 16 + m16;
    const float4* g = (const float4*)(nb + (base + row) * 64 + kb * 32 + q * 8);
    xv[it][0] = g[0];
    xv[it][1] = g[1];
  }
  int   sv  = (tid < ROWS) ? seg[base + tid] : 0;
  float bvv = (tid < 64)   ? b1g[tid]        : 0.f;

  // ---- W1 fragments: async global->LDS, 1 KB per instruction, no VGPR trip
  #pragma unroll
  for (int c = 0; c < 2; ++c) {
    int chunk = w * 2 + c;  // 8 x 1KB chunks, wave-distributed
    __builtin_amdgcn_global_load_lds(
        (const __attribute__((address_space(1))) void*)(w1pack + chunk * 512 + lane * 8),
        (__attribute__((address_space(3))) void*)(&u.s.Wfr[chunk * 512]),
        16, 0, 0);
  }

  // ---- LDS writes (after loads issued)
  if (tid < ROWS) sid[tid] = sv;
  if (tid < 64)  biasf[tid] = bvv;
  #pragma unroll
  for (int it = 0; it < 4; ++it) {
    int tile = 2 * w + (it >> 1), kb = it & 1;
    float4 v0 = xv[it][0], v1 = xv[it][1];
    bf16x8 p = { (bf16_t)v0.x, (bf16_t)v0.y, (bf16_t)v0.z, (bf16_t)v0.w,
                 (bf16_t)v1.x, (bf16_t)v1.y, (bf16_t)v1.z, (bf16_t)v1.w };
    *(bf16x8*)&u.s.Afr[((tile * 2 + kb) * 64 + lane) * 8] = p;
  }
  __syncthreads();   // drains vmcnt (global_load_lds) + lgkm

  // ---- fragment loads: lane*16 contiguous -> zero bank conflicts
  bf16x8 afr[2][2], bfr[4][2];
  #pragma unroll
  for (int tm = 0; tm < 2; ++tm)
    #pragma unroll
    for (int kb = 0; kb < 2; ++kb)
      afr[tm][kb] = *(const bf16x8*)&u.s.Afr[(((2 * w + tm) * 2 + kb) * 64 + lane) * 8];
  #pragma unroll
  for (int tn = 0; tn < 4; ++tn)
    #pragma unroll
    for (int kb = 0; kb < 2; ++kb)
      bfr[tn][kb] = *(const bf16x8*)&u.s.Wfr[((tn * 2 + kb) * 64 + lane) * 8];

  f32x4 acc[2][4];
  #pragma unroll
  for (int tm = 0; tm < 2; ++tm)
    #pragma unroll
    for (int tn = 0; tn < 4; ++tn) {
      f32x4 a = {0.f, 0.f, 0.f, 0.f};
      a = __builtin_amdgcn_mfma_f32_16x16x32_bf16(afr[tm][0], bfr[tn][0], a, 0, 0, 0);
      a = __builtin_amdgcn_mfma_f32_16x16x32_bf16(afr[tm][1], bfr[tn][1], a, 0, 0, 0);
      acc[tm][tn] = a;
    }
  __syncthreads();   // all frag reads done; outb may overwrite frag memory

  // ---- H1 (bias+relu) -> outb fp32; D layout: row=q*4+i, col=tn*16+m16
  const int rb = w * 32;
  #pragma unroll
  for (int tm = 0; tm < 2; ++tm)
    #pragma unroll
    for (int tn = 0; tn < 4; ++tn) {
      float bv = biasf[tn * 16 + m16];
      #pragma unroll
      for (int i = 0; i < 4; ++i)
        u.outb[(rb + tm * 16 + q * 4 + i) * SO + tn * 16 + m16] =
            fmaxf(acc[tm][tn][i] + bv, 0.f);
    }

  // ---- segmented reduction: wave owns rows [rb,rb+32), lane owns col=lane.
  // sorted ids -> run detection; one wave-atomic per run (+1 lane-0 cnt add).
  float racc = 0.f;
  int runlen = 0;
  for (int r = rb; r < rb + 32; ++r) {
    racc += u.outb[r * SO + lane];
    ++runlen;
    int sr = sid[r];
    if (r == rb + 31 || sid[r + 1] != sr) {
      atomicAdd(summH1 + (long)sr * 64 + lane, racc);
      if (lane == 0) atomicAdd(cnt + sr, (float)runlen);
      racc = 0.f;
      runlen = 0;
    }
  }
}

// ---------------------------------------------------------------------------
// rho: fp32 throughout. Prologue computes the GEMM2 fold redundantly per
// block (Wc = phi_w2 @ rho_w1 into LDS, bc = phi_b2 @ rho_w1): 196 parallel
// blocks, coalesced cache-hot loads (~2-3 us) -- replaces the serial 2-block
// prep fold that cost 10-20 us ahead of phi in R2.
// h = relu(summH1 @ Wc + cnt*bc + rho_b1); out = h @ rho_w2 + rho_b2.
// ---------------------------------------------------------------------------
__global__ __launch_bounds__(256) void rho_kernel(
    const float* __restrict__ summH1, const float* __restrict__ cnt,
    const float* __restrict__ w2g,  const float* __restrict__ b2g,
    const float* __restrict__ rw1g, const float* __restrict__ rb1g,
    const float* __restrict__ rw2g, const float* __restrict__ rb2g,
    float* __restrict__ out)
{
  __shared__ float sW[64 * 64];    // Wc, layout [k][n]
  __shared__ float sbc[64], sb1[64], sw2[128], sb2[2];
  const int tid = threadIdx.x;

  // Wc[k][n] = sum_o phi_w2[k][o] * rho_w1[o][n]; lanes walk n -> coalesced.
  for (int i = tid; i < 4096; i += 256) {
    int h = i >> 6, n = i & 63;
    float s = 0.f;
    #pragma unroll 8
    for (int o = 0; o < 64; ++o) s = fmaf(w2g[h * 64 + o], rw1g[o * 64 + n], s);
    sW[i] = s;
  }
  if (tid < 64) {
    float s = 0.f;
    #pragma unroll 8
    for (int o = 0; o < 64; ++o) s = fmaf(b2g[o], rw1g[o * 64 + tid], s);
    sbc[tid] = s;
    sb1[tid] = rb1g[tid];
  }
  if (tid < 128) sw2[tid] = rw2g[tid];
  if (tid < 2)   sb2[tid] = rb2g[tid];
  __syncthreads();

  int a = blockIdx.x * 256 + tid;
  if (a >= N_AGENTS) return;

  float x[64];
  const float4* xr = (const float4*)(summH1 + (long)a * 64);
  #pragma unroll
  for (int i = 0; i < 16; ++i) {
    float4 v = xr[i];
    x[4 * i] = v.x; x[4 * i + 1] = v.y; x[4 * i + 2] = v.z; x[4 * i + 3] = v.w;
  }
  float c = cnt[a];

  float o0 = sb2[0], o1 = sb2[1];
  for (int n = 0; n < 64; ++n) {
    float a0 = fmaf(c, sbc[n], sb1[n]), a1 = 0.f, a2 = 0.f, a3 = 0.f;
    #pragma unroll
    for (int k = 0; k < 64; k += 4) {
      a0 = fmaf(x[k],     sW[(k)     * 64 + n], a0);
      a1 = fmaf(x[k + 1], sW[(k + 1) * 64 + n], a1);
      a2 = fmaf(x[k + 2], sW[(k + 2) * 64 + n], a2);
      a3 = fmaf(x[k + 3], sW[(k + 3) * 64 + n], a3);
    }
    float h = fmaxf((a0 + a1) + (a2 + a3), 0.f);
    o0 = fmaf(h, sw2[2 * n],     o0);
    o1 = fmaf(h, sw2[2 * n + 1], o1);
  }
  *(float2*)(out + (long)a * 2) = make_float2(o0, o1);
}

// ---------------------------------------------------------------------------
extern "C" void kernel_launch(void* const* d_in, const int* in_sizes, int n_in,
                              void* d_out, int out_size, void* d_ws, size_t ws_size,
                              hipStream_t stream) {
  const float* neighbors = (const float*)d_in[0];
  const float* phi_w1    = (const float*)d_in[1];
  const float* phi_b1    = (const float*)d_in[2];
  const float* phi_w2    = (const float*)d_in[3];
  const float* phi_b2    = (const float*)d_in[4];
  const float* rho_w1    = (const float*)d_in[5];
  const float* rho_b1    = (const float*)d_in[6];
  const float* rho_w2    = (const float*)d_in[7];
  const float* rho_b2    = (const float*)d_in[8];
  const int*   seg       = (const int*)d_in[9];
  float* out = (float*)d_out;

  float* ws     = (float*)d_ws;
  float* summH1 = ws + WS_SUMM;
  float* cntp   = ws + WS_CNT;
  unsigned short* w1pack = (unsigned short*)(ws + WS_W1PK);

  hipMemsetAsync(ws, 0, (size_t)WS_ZERO_F * sizeof(float), stream);
  prep_kernel<<<1, 256, 0, stream>>>(phi_w1, w1pack);
  phi_kernel<<<PHI_BLOCKS, 256, 0, stream>>>(neighbors, phi_b1, seg, w1pack,
                                             summH1, cntp);
  rho_kernel<<<(N_AGENTS + 255) / 256, 256, 0, stream>>>(
      summH1, cntp, phi_w2, phi_b2, rho_w1, rho_b1, rho_w2, rho_b2, out);
}

// Round 4
// 626.342 us; speedup vs baseline: 1.0041x; 1.0002x over previous
//
#include <hip/hip_runtime.h>
#include <hip/hip_bf16.h>

#define N_AGENTS 50000
#define N_NEI    1600000
#define ROWS     128
#define PHI_BLOCKS (N_NEI / ROWS)   // 12500, exact

typedef __bf16 bf16_t;
typedef __attribute__((ext_vector_type(8))) __bf16 bf16x8;
typedef __attribute__((ext_vector_type(4))) __bf16 bf16x4;
typedef __attribute__((ext_vector_type(4))) float  f32x4;

#define SA 72   // bf16 X-tile leading dim; frag-read phases land 2-way (free)
#define SO 66   // fp32 outb leading dim: exact 2-way on reads (free)

// ws layout (float units)
#define WS_SUMM   0            // 50000*64 = 3,200,000 f  (atomic-accumulated pooled H1)
#define WS_CNT    3200000      // 50000 f                 (per-agent neighbor count)
#define WS_W1PK   3250000      // 4096 bf16 = 2048 f, byte off 13,000,000 (16B aligned)
#define WS_ZERO_F 3250000      // floats to zero (summ + cnt)

// ---------------------------------------------------------------------------
// prep: single tiny block packs W1^T (bf16) into MFMA B-fragment order:
//   frag[tn=n>>4][kb=k>>5][lane=(n&15)+16*((k>>3)&3)][j=k&7]
// so phi stages it with global_load_lds (wave-uniform base + lane*16) and
// reads fragments as lane-contiguous ds_read_b128 (zero bank conflicts).
// ---------------------------------------------------------------------------
__global__ __launch_bounds__(256) void prep_kernel(
    const float* __restrict__ w1g, unsigned short* __restrict__ w1pack)
{
  const int tid = threadIdx.x;
  for (int i = tid; i < 4096; i += 256) {
    int k = i >> 6, n = i & 63;              // w1g is [k][n] row-major
    int tn = n >> 4, kb = k >> 5;
    int l  = (n & 15) + 16 * ((k >> 3) & 3);
    int j  = k & 7;
    bf16_t bv = (bf16_t)w1g[i];
    w1pack[((tn * 2 + kb) * 64 + l) * 8 + j] = *(unsigned short*)&bv;
  }
}

// ---------------------------------------------------------------------------
// phi: per block of 128 sorted rows: H1 = relu(X@W1+b1) via bf16 MFMA, then
// per-wave segmented column-sum of H1 -> atomicAdd into summH1 + cnt.
// R4: X is staged with PERFECTLY CONTIGUOUS global loads (1 KB/instruction,
// the R1 pattern) into a row-major bf16 tile. R2/R3 loaded X in fragment
// order (16-row strided half-lines) and regressed ~20 us on the 409.6 MB
// stream; A-frag reads from the row-major tile cost only a free 2-way phase
// conflict. B-frags stay DMA-staged + conflict-free.
// ---------------------------------------------------------------------------
__global__ __launch_bounds__(256, 4) void phi_kernel(
    const float* __restrict__ nb, const float* __restrict__ b1g,
    const int* __restrict__ seg, const unsigned short* __restrict__ w1pack,
    float* __restrict__ summH1, float* __restrict__ cnt)
{
  __shared__ __align__(16) union {
    struct {
      bf16_t A[ROWS * SA];      // 18432 B : X tile, row-major bf16
      bf16_t Wfr[8 * 64 * 8];   //  8192 B : W1 B-fragments [tn*2+kb][lane][j]
    } s;
    float outb[ROWS * SO];      // 33792 B : H1 fp32 (aliases A + Wfr + 7 KB)
  } u;
  __shared__ float biasf[64];
  __shared__ int sid[ROWS];

  const int tid  = threadIdx.x;
  const int w    = tid >> 6;
  const int lane = tid & 63;
  const int m16  = lane & 15;
  const int q    = lane >> 4;
  const long base = (long)blockIdx.x * ROWS;

  // ---- issue ALL global loads first: 8 contiguous dwordx4 (1 KB/instr/wave)
  const float4* np4 = (const float4*)(nb + base * 64);
  float4 xv[8];
  #pragma unroll
  for (int it = 0; it < 8; ++it) xv[it] = np4[tid + it * 256];
  int   sv  = (tid < ROWS) ? seg[base + tid] : 0;
  float bvv = (tid < 64)   ? b1g[tid]        : 0.f;

  // ---- W1 fragments: async global->LDS, 1 KB per instruction
  #pragma unroll
  for (int c = 0; c < 2; ++c) {
    int chunk = w * 2 + c;  // 8 x 1KB chunks, wave-distributed
    __builtin_amdgcn_global_load_lds(
        (const __attribute__((address_space(1))) void*)(w1pack + chunk * 512 + lane * 8),
        (__attribute__((address_space(3))) void*)(&u.s.Wfr[chunk * 512]),
        16, 0, 0);
  }

  // ---- LDS writes (after all loads issued)
  if (tid < ROWS) sid[tid] = sv;
  if (tid < 64)  biasf[tid] = bvv;
  #pragma unroll
  for (int it = 0; it < 8; ++it) {
    int j = tid + it * 256;               // row = j>>4, col = (j&15)*4
    float4 v = xv[it];
    bf16x4 p = { (bf16_t)v.x, (bf16_t)v.y, (bf16_t)v.z, (bf16_t)v.w };
    *(bf16x4*)&u.s.A[(j >> 4) * SA + (j & 15) * 4] = p;
  }
  __syncthreads();   // drains vmcnt (global_load_lds) + lgkm

  // ---- fragment loads
  // A: row-major tile, start dword = row*36 + kb*16 + q*4 -> 2-way phases (free)
  bf16x8 afr[2][2], bfr[4][2];
  #pragma unroll
  for (int tm = 0; tm < 2; ++tm)
    #pragma unroll
    for (int kb = 0; kb < 2; ++kb)
      afr[tm][kb] = *(const bf16x8*)
          &u.s.A[((2 * w + tm) * 16 + m16) * SA + kb * 32 + q * 8];
  // B: lane-contiguous (zero conflicts)
  #pragma unroll
  for (int tn = 0; tn < 4; ++tn)
    #pragma unroll
    for (int kb = 0; kb < 2; ++kb)
      bfr[tn][kb] = *(const bf16x8*)&u.s.Wfr[((tn * 2 + kb) * 64 + lane) * 8];

  f32x4 acc[2][4];
  #pragma unroll
  for (int tm = 0; tm < 2; ++tm)
    #pragma unroll
    for (int tn = 0; tn < 4; ++tn) {
      f32x4 a = {0.f, 0.f, 0.f, 0.f};
      a = __builtin_amdgcn_mfma_f32_16x16x32_bf16(afr[tm][0], bfr[tn][0], a, 0, 0, 0);
      a = __builtin_amdgcn_mfma_f32_16x16x32_bf16(afr[tm][1], bfr[tn][1], a, 0, 0, 0);
      acc[tm][tn] = a;
    }
  __syncthreads();   // all frag reads done; outb may overwrite A/Wfr memory

  // ---- H1 (bias+relu) -> outb fp32; D layout: row=q*4+i, col=tn*16+m16
  const int rb = w * 32;
  #pragma unroll
  for (int tm = 0; tm < 2; ++tm)
    #pragma unroll
    for (int tn = 0; tn < 4; ++tn) {
      float bv = biasf[tn * 16 + m16];
      #pragma unroll
      for (int i = 0; i < 4; ++i)
        u.outb[(rb + tm * 16 + q * 4 + i) * SO + tn * 16 + m16] =
            fmaxf(acc[tm][tn][i] + bv, 0.f);
    }

  // ---- segmented reduction: wave owns rows [rb,rb+32), lane owns col=lane.
  // sorted ids -> run detection; one wave-atomic per run (+1 lane-0 cnt add).
  float racc = 0.f;
  int runlen = 0;
  for (int r = rb; r < rb + 32; ++r) {
    racc += u.outb[r * SO + lane];
    ++runlen;
    int sr = sid[r];
    if (r == rb + 31 || sid[r + 1] != sr) {
      atomicAdd(summH1 + (long)sr * 64 + lane, racc);
      if (lane == 0) atomicAdd(cnt + sr, (float)runlen);
      racc = 0.f;
      runlen = 0;
    }
  }
}

// ---------------------------------------------------------------------------
// rho: fp32 throughout. Prologue computes the GEMM2 fold redundantly per
// block (Wc = phi_w2 @ rho_w1 into LDS, bc = phi_b2 @ rho_w1) -- 196
// parallel blocks, coalesced cache-hot loads.
// h = relu(summH1 @ Wc + cnt*bc + rho_b1); out = h @ rho_w2 + rho_b2.
// ---------------------------------------------------------------------------
__global__ __launch_bounds__(256) void rho_kernel(
    const float* __restrict__ summH1, const float* __restrict__ cnt,
    const float* __restrict__ w2g,  const float* __restrict__ b2g,
    const float* __restrict__ rw1g, const float* __restrict__ rb1g,
    const float* __restrict__ rw2g, const float* __restrict__ rb2g,
    float* __restrict__ out)
{
  __shared__ float sW[64 * 64];    // Wc, layout [k][n]
  __shared__ float sbc[64], sb1[64], sw2[128], sb2[2];
  const int tid = threadIdx.x;

  // Wc[k][n] = sum_o phi_w2[k][o] * rho_w1[o][n]; lanes walk n -> coalesced.
  for (int i = tid; i < 4096; i += 256) {
    int h = i >> 6, n = i & 63;
    float s = 0.f;
    #pragma unroll 8
    for (int o = 0; o < 64; ++o) s = fmaf(w2g[h * 64 + o], rw1g[o * 64 + n], s);
    sW[i] = s;
  }
  if (tid < 64) {
    float s = 0.f;
    #pragma unroll 8
    for (int o = 0; o < 64; ++o) s = fmaf(b2g[o], rw1g[o * 64 + tid], s);
    sbc[tid] = s;
    sb1[tid] = rb1g[tid];
  }
  if (tid < 128) sw2[tid] = rw2g[tid];
  if (tid < 2)   sb2[tid] = rb2g[tid];
  __syncthreads();

  int a = blockIdx.x * 256 + tid;
  if (a >= N_AGENTS) return;

  float x[64];
  const float4* xr = (const float4*)(summH1 + (long)a * 64);
  #pragma unroll
  for (int i = 0; i < 16; ++i) {
    float4 v = xr[i];
    x[4 * i] = v.x; x[4 * i + 1] = v.y; x[4 * i + 2] = v.z; x[4 * i + 3] = v.w;
  }
  float c = cnt[a];

  float o0 = sb2[0], o1 = sb2[1];
  for (int n = 0; n < 64; ++n) {
    float a0 = fmaf(c, sbc[n], sb1[n]), a1 = 0.f, a2 = 0.f, a3 = 0.f;
    #pragma unroll
    for (int k = 0; k < 64; k += 4) {
      a0 = fmaf(x[k],     sW[(k)     * 64 + n], a0);
      a1 = fmaf(x[k + 1], sW[(k + 1) * 64 + n], a1);
      a2 = fmaf(x[k + 2], sW[(k + 2) * 64 + n], a2);
      a3 = fmaf(x[k + 3], sW[(k + 3) * 64 + n], a3);
    }
    float h = fmaxf((a0 + a1) + (a2 + a3), 0.f);
    o0 = fmaf(h, sw2[2 * n],     o0);
    o1 = fmaf(h, sw2[2 * n + 1], o1);
  }
  *(float2*)(out + (long)a * 2) = make_float2(o0, o1);
}

// ---------------------------------------------------------------------------
extern "C" void kernel_launch(void* const* d_in, const int* in_sizes, int n_in,
                              void* d_out, int out_size, void* d_ws, size_t ws_size,
                              hipStream_t stream) {
  const float* neighbors = (const float*)d_in[0];
  const float* phi_w1    = (const float*)d_in[1];
  const float* phi_b1    = (const float*)d_in[2];
  const float* phi_w2    = (const float*)d_in[3];
  const float* phi_b2    = (const float*)d_in[4];
  const float* rho_w1    = (const float*)d_in[5];
  const float* rho_b1    = (const float*)d_in[6];
  const float* rho_w2    = (const float*)d_in[7];
  const float* rho_b2    = (const float*)d_in[8];
  const int*   seg       = (const int*)d_in[9];
  float* out = (float*)d_out;

  float* ws     = (float*)d_ws;
  float* summH1 = ws + WS_SUMM;
  float* cntp   = ws + WS_CNT;
  unsigned short* w1pack = (unsigned short*)(ws + WS_W1PK);

  hipMemsetAsync(ws, 0, (size_t)WS_ZERO_F * sizeof(float), stream);
  prep_kernel<<<1, 256, 0, stream>>>(phi_w1, w1pack);
  phi_kernel<<<PHI_BLOCKS, 256, 0, stream>>>(neighbors, phi_b1, seg, w1pack,
                                             summH1, cntp);
  rho_kernel<<<(N_AGENTS + 255) / 256, 256, 0, stream>>>(
      summH1, cntp, phi_w2, phi_b2, rho_w1, rho_b1, rho_w2, rho_b2, out);
}